// Round 6
// baseline (209.059 us; speedup 1.0000x reference)
//
#include <hip/hip_runtime.h>
#include <math.h>

typedef __bf16 bf16_t;
typedef bf16_t bf16x2 __attribute__((ext_vector_type(2)));
typedef bf16_t bf16x4 __attribute__((ext_vector_type(4)));
typedef bf16_t bf16x8 __attribute__((ext_vector_type(8)));
typedef float f32x4 __attribute__((ext_vector_type(4)));

#define MFMA16(a,b,c) __builtin_amdgcn_mfma_f32_16x16x32_bf16((a),(b),(c),0,0,0)

#define ND 256
#define NQ 512
#define NF 50
#define L2E 1.44269504f
#define SHIFT 64.0f

// bf16-element offsets
#define SENT_E 0        // [64 f][268 i]  sen^T raw (rows 50..63 zero)
#define PD0_E  17152    // [256 i][72 j]  E-half buf0 (setup alias: sen[i][72f]+bias)
#define PD1_E  35584    // [256 i][72 j]  E-half buf1
#define QW3_E  54016    // 2 x [64 j][72 f] (q*w3*L2E + bias cols; 52..63 zero)
#define QTT_E  63232    // [64 f][72 j]   q^T * sqrt(ci)  (rows 50..63 zero)
#define KL0_E  17152    // epilogue: [256 i][40 i'] bf16 chunk buf0 (aliases PD0)
#define KL1_E  27392    // chunk buf1
#define PART_B  135680  // f32 [16 w][64 j] col partials
#define STATS_B 139776  // f32: qterm[512], sqci[64], rinv[256]
#define LDS_BYTES 143104

#define ST_QTERM 0
#define ST_SQCI  512
#define ST_RINV  576

__launch_bounds__(1024, 1)
__global__ void ca6_kernel(const float* __restrict__ query,
                           const float* __restrict__ doc,
                           const float* __restrict__ W,
                           float* __restrict__ out)
{
    extern __shared__ char smem[];
    bf16_t* lb = (bf16_t*)smem;
    float* part  = (float*)(smem + PART_B);
    float* stats = (float*)(smem + STATS_B);

    const int tid = threadIdx.x;
    const int w = tid >> 6, l = tid & 63, ln = l & 15, lg = l >> 4;
    const int s = blockIdx.x;
    const float* sen_g = doc + (size_t)s * (ND * NF);

    auto stageQW3 = [&](int jt, int buf, int tbase, int tn) {
        const int j0 = jt * 64;
        bf16_t* dst = lb + QW3_E + buf * 4608;
        for (int e = tid - tbase; e < 1664; e += tn) {
            int jj = e / 26, c = e - jj * 26;
            if (c < 25) {
                float2 v = ((const float2*)query)[(j0 + jj) * 25 + c];
                bf16x2 p;
                p[0] = (bf16_t)(v.x * W[100 + 2 * c] * L2E);
                p[1] = (bf16_t)(v.y * W[100 + 2 * c + 1] * L2E);
                *(bf16x2*)&dst[jj * 72 + 2 * c] = p;
            } else {
                bf16x2 p;
                p[0] = (bf16_t)(stats[ST_QTERM + j0 + jj] * L2E);
                p[1] = (bf16_t)L2E;
                *(bf16x2*)&dst[jj * 72 + 50] = p;
            }
        }
    };
    auto stageQTT = [&](int jt) {        // q^T * sqrt(ci)
        const int j0 = jt * 64;
        for (int e = tid; e < 1600; e += 1024) {
            int c = e >> 6, jj = e & 63;
            float sq = stats[ST_SQCI + jj];
            float2 v = ((const float2*)query)[(j0 + jj) * 25 + c];
            lb[QTT_E + (2 * c) * 72 + jj]     = (bf16_t)(v.x * sq);
            lb[QTT_E + (2 * c + 1) * 72 + jj] = (bf16_t)(v.y * sq);
        }
    };

    // ---------------- setup phase 1 (no LDS cross-reads) ----------------
    for (int e = tid; e < 938; e += 1024) {               // SENT pad rows 50..63
        int f = 50 + e / 67, c4 = (e - (e / 67) * 67) * 4;
        *(bf16x4*)&lb[SENT_E + f * 268 + c4] = (bf16x4){(bf16_t)0.f,(bf16_t)0.f,(bf16_t)0.f,(bf16_t)0.f};
    }
    for (int e = tid; e < 768; e += 1024) {               // sen K-pad cols 52..63
        int i = e / 3, c4 = 52 + (e - (e / 3) * 3) * 4;
        *(bf16x4*)&lb[PD0_E + i * 72 + c4] = (bf16x4){(bf16_t)0.f,(bf16_t)0.f,(bf16_t)0.f,(bf16_t)0.f};
    }
    for (int e = tid; e < 384; e += 1024) {               // QW3 pad cols (both bufs)
        int b = e / 192, r = e - b * 192;
        int jj = r / 3, c4 = 52 + (r - (r / 3) * 3) * 4;
        *(bf16x4*)&lb[QW3_E + b * 4608 + jj * 72 + c4] = (bf16x4){(bf16_t)0.f,(bf16_t)0.f,(bf16_t)0.f,(bf16_t)0.f};
    }
    for (int e = tid; e < 252; e += 1024) {               // QTT pad rows 50..63
        int f = 50 + e / 18, c4 = (e - (e / 18) * 18) * 4;
        *(bf16x4*)&lb[QTT_E + f * 72 + c4] = (bf16x4){(bf16_t)0.f,(bf16_t)0.f,(bf16_t)0.f,(bf16_t)0.f};
    }
    for (int e = tid; e < 256 * 25; e += 1024) {          // doc -> sen[i][f] + sen^T
        int i = e / 25, c = e - i * 25;
        float2 v = ((const float2*)sen_g)[i * 25 + c];
        bf16x2 p; p[0] = (bf16_t)v.x; p[1] = (bf16_t)v.y;
        *(bf16x2*)&lb[PD0_E + i * 72 + 2 * c] = p;
        lb[SENT_E + (2 * c) * 268 + i]     = p[0];
        lb[SENT_E + (2 * c + 1) * 268 + i] = p[1];
    }
    if (tid < NQ) {                                       // qterm = q . w2
        float acc = 0.f;
        #pragma unroll
        for (int c = 0; c < 25; ++c) {
            float2 v = ((const float2*)query)[tid * 25 + c];
            acc += v.x * W[NF + 2 * c] + v.y * W[NF + 2 * c + 1];
        }
        stats[ST_QTERM + tid] = acc;
    }
    if (tid < ND) {                                       // bias cols: 1, senw1
        float acc = 0.f;
        #pragma unroll
        for (int f = 0; f < NF; ++f) acc += sen_g[tid * NF + f] * W[f];
        lb[PD0_E + tid * 72 + 50] = (bf16_t)1.0f;
        lb[PD0_E + tid * 72 + 51] = (bf16_t)acc;
    }
    __syncthreads();

    // ---------------- setup phase 2 (qterm now visible) ----------------
    bf16x8 aS[2];
    #pragma unroll
    for (int ks = 0; ks < 2; ++ks)
        aS[ks] = *(bf16x8*)&lb[PD0_E + (w * 16 + ln) * 72 + lg * 8 + ks * 32];
    stageQW3(0, 0, 0, 1024);
    __syncthreads();

    // ---------------- single fused pass ----------------
    f32x4 accD[4];
    f32x4 K[16];
    #pragma unroll
    for (int nf = 0; nf < 4; ++nf) accD[nf] = (f32x4){0.f, 0.f, 0.f, 0.f};
    #pragma unroll
    for (int ib = 0; ib < 16; ++ib) K[ib] = (f32x4){0.f, 0.f, 0.f, 0.f};
    float rpart[4] = {0.f, 0.f, 0.f, 0.f};

    for (int jt = 0; jt < 8; ++jt) {
        const bf16_t* qb = lb + QW3_E + (jt & 1) * 4608;
        bf16_t* pd = lb + ((jt & 1) ? PD1_E : PD0_E);

        f32x4 acc[4];
        #pragma unroll
        for (int nf = 0; nf < 4; ++nf) acc[nf] = (f32x4){-SHIFT, -SHIFT, -SHIFT, -SHIFT};
        #pragma unroll
        for (int ks = 0; ks < 2; ++ks)
            #pragma unroll
            for (int nf = 0; nf < 4; ++nf) {
                bf16x8 b = *(bf16x8*)&qb[(nf * 16 + ln) * 72 + lg * 8 + ks * 32];
                acc[nf] = MFMA16(aS[ks], b, acc[nf]);
            }

        float ev[4][4];
        #pragma unroll
        for (int nf = 0; nf < 4; ++nf) {
            #pragma unroll
            for (int r = 0; r < 4; ++r) {
                ev[nf][r] = exp2f(acc[nf][r]);
                rpart[r] += ev[nf][r];
            }
            float cp = (ev[nf][0] + ev[nf][1]) + (ev[nf][2] + ev[nf][3]);
            cp += __shfl_xor(cp, 16);
            cp += __shfl_xor(cp, 32);
            if (lg == 0) part[w * 64 + nf * 16 + ln] = cp;
        }
        __syncthreads();                                  // A: partials ready

        if (w == 0) {
            float cs = 0.f;
            #pragma unroll
            for (int ww = 0; ww < 16; ++ww) cs += part[ww * 64 + l];
            stats[ST_SQCI + l] = rsqrtf(cs);
        } else if (jt < 7) {
            stageQW3(jt + 1, (jt + 1) & 1, 64, 960);
        }
        __syncthreads();                                  // B: sqci ready

        #pragma unroll
        for (int nf = 0; nf < 4; ++nf) {
            float sq = stats[ST_SQCI + nf * 16 + ln];
            #pragma unroll
            for (int r = 0; r < 4; ++r)
                pd[(w * 16 + lg * 4 + r) * 72 + nf * 16 + ln] = (bf16_t)(ev[nf][r] * sq);
        }
        stageQTT(jt);
        __syncthreads();                                  // C: E-half + QTT ready

        bf16x8 aP[2];
        #pragma unroll
        for (int ks = 0; ks < 2; ++ks) {
            aP[ks] = *(bf16x8*)&pd[(w * 16 + ln) * 72 + lg * 8 + ks * 32];
            #pragma unroll
            for (int nf = 0; nf < 4; ++nf) {
                bf16x8 bq = *(bf16x8*)&lb[QTT_E + (nf * 16 + ln) * 72 + lg * 8 + ks * 32];
                accD[nf] = MFMA16(aP[ks], bq, accD[nf]);
            }
        }
        #pragma unroll
        for (int ib = 0; ib < 16; ++ib)
            #pragma unroll
            for (int ks = 0; ks < 2; ++ks) {
                bf16x8 bb = *(bf16x8*)&pd[(ib * 16 + ln) * 72 + lg * 8 + ks * 32];
                K[ib] = MFMA16(aP[ks], bb, K[ib]);
            }
    }

    // ---------------- rinv ----------------
    #pragma unroll
    for (int r = 0; r < 4; ++r) {
        float v = rpart[r];
        v += __shfl_xor(v, 1);
        v += __shfl_xor(v, 2);
        v += __shfl_xor(v, 4);
        v += __shfl_xor(v, 8);
        if (ln == 0) stats[ST_RINV + w * 16 + lg * 4 + r] = 1.f / v;
    }
    __syncthreads();

    // ---------------- aQ2D = (ri*K) @ sen^T, 8 chunks ----------------
    f32x4 accQ[4];
    #pragma unroll
    for (int nf = 0; nf < 4; ++nf) accQ[nf] = (f32x4){0.f, 0.f, 0.f, 0.f};
    #pragma unroll
    for (int kt = 0; kt < 8; ++kt) {
        bf16_t* kl = lb + ((kt & 1) ? KL1_E : KL0_E);
        #pragma unroll
        for (int h = 0; h < 2; ++h) {
            const int ib = 2 * kt + h;
            float riv = stats[ST_RINV + ib * 16 + ln];
            #pragma unroll
            for (int r = 0; r < 4; ++r)
                kl[(w * 16 + lg * 4 + r) * 40 + h * 16 + ln] = (bf16_t)(K[ib][r] * riv);
        }
        __syncthreads();
        bf16x8 aK = *(bf16x8*)&kl[(w * 16 + ln) * 40 + lg * 8];
        #pragma unroll
        for (int nf = 0; nf < 4; ++nf) {
            bf16x8 b = *(bf16x8*)&lb[SENT_E + (nf * 16 + ln) * 268 + kt * 32 + lg * 8];
            accQ[nf] = MFMA16(aK, b, accQ[nf]);
        }
    }
    __syncthreads();

    // ---------------- epilogue ----------------
    float* ea = (float*)smem;                  // [256][68]
    float* eb = (float*)(smem + 69632);
    #pragma unroll
    for (int nf = 0; nf < 4; ++nf)
        #pragma unroll
        for (int r = 0; r < 4; ++r) {
            ea[(w * 16 + lg * 4 + r) * 68 + nf * 16 + ln] = accD[nf][r];
            eb[(w * 16 + lg * 4 + r) * 68 + nf * 16 + ln] = accQ[nf][r];
        }
    __syncthreads();
    const size_t ob0 = (size_t)s * (ND * 200);
    #pragma unroll
    for (int seg = 0; seg < 4; ++seg) {
        for (int v = tid; v < 6400; v += 1024) {
            int i = v / 25, c = v - (v / 25) * 25;
            int f = 2 * c;
            float2 o;
            if (seg == 0) {
                o = *(const float2*)&sen_g[i * 50 + f];
            } else if (seg == 1) {
                o.x = ea[i * 68 + f]; o.y = ea[i * 68 + f + 1];
            } else if (seg == 2) {
                float2 d = *(const float2*)&sen_g[i * 50 + f];
                o.x = d.x * ea[i * 68 + f]; o.y = d.y * ea[i * 68 + f + 1];
            } else {
                float2 d = *(const float2*)&sen_g[i * 50 + f];
                o.x = d.x * eb[i * 68 + f]; o.y = d.y * eb[i * 68 + f + 1];
            }
            *(float2*)&out[ob0 + (size_t)i * 200 + seg * 50 + f] = o;
        }
    }
}

extern "C" void kernel_launch(void* const* d_in, const int* in_sizes, int n_in,
                              void* d_out, int out_size, void* d_ws, size_t ws_size,
                              hipStream_t stream) {
    const float* query = (const float*)d_in[0];
    const float* doc   = (const float*)d_in[1];
    const float* W     = (const float*)d_in[2];
    float* out = (float*)d_out;
    (void)d_ws; (void)ws_size; (void)n_in; (void)in_sizes; (void)out_size;

    hipFuncSetAttribute((const void*)ca6_kernel,
                        hipFuncAttributeMaxDynamicSharedMemorySize,
                        LDS_BYTES);
    ca6_kernel<<<dim3(512), dim3(1024), LDS_BYTES, stream>>>(query, doc, W, out);
}

// Round 7
// 188.500 us; speedup vs baseline: 1.1091x; 1.1091x over previous
//
#include <hip/hip_runtime.h>
#include <math.h>

typedef __bf16 bf16_t;
typedef bf16_t bf16x2 __attribute__((ext_vector_type(2)));
typedef bf16_t bf16x4 __attribute__((ext_vector_type(4)));
typedef bf16_t bf16x8 __attribute__((ext_vector_type(8)));
typedef float f32x4 __attribute__((ext_vector_type(4)));

#define MFMA16(a,b,c) __builtin_amdgcn_mfma_f32_16x16x32_bf16((a),(b),(c),0,0,0)

#define ND 256
#define NQ 512
#define NF 50
#define L2E 1.44269504f
#define SHIFT 64.0f

// bf16-element offsets
#define SENT_E 0        // [64 f][264 i]  sen^T raw (rows 50..63 zero)
#define PD0_E  16896    // [256 i][72 j]  raw-E buf0 (setup alias: sen[i][72f]+bias)
#define PD1_E  35328    // [256 i][72 j]  raw-E buf1
#define QW3_E  53760    // 2 x [64 j][72 f] (q*w3*L2E + bias cols; 52..63 zero)
#define QTT_E  62976    // 2 x [64 f][72 j] raw q^T (rows 50..63 zero)
#define KL0_E  16896    // epilogue: [256 i][40] bf16 chunk buf0 (aliases PD0)
#define KL1_E  27136    // chunk buf1
#define PART_B  144384  // f32 [16 w][64 j] col partials
#define STATS_B 148480  // f32: qterm[512], ci[64], rinv[256]
#define LDS_BYTES 151808

#define ST_QTERM 0
#define ST_CI    512
#define ST_RINV  576

__launch_bounds__(1024, 4)
__global__ void ca7_kernel(const float* __restrict__ query,
                           const float* __restrict__ doc,
                           const float* __restrict__ W,
                           float* __restrict__ out)
{
    extern __shared__ char smem[];
    bf16_t* lb = (bf16_t*)smem;
    float* part  = (float*)(smem + PART_B);
    float* stats = (float*)(smem + STATS_B);

    const int tid = threadIdx.x;
    const int w = tid >> 6, l = tid & 63, ln = l & 15, lg = l >> 4;
    const int s = blockIdx.x;
    const float* sen_g = doc + (size_t)s * (ND * NF);

    auto stageQW3 = [&](int jt, int buf, int tbase, int tn) {
        const int j0 = jt * 64;
        bf16_t* dst = lb + QW3_E + buf * 4608;
        for (int e = tid - tbase; e < 1664; e += tn) {
            int jj = e / 26, c = e - jj * 26;
            if (c < 25) {
                float2 v = ((const float2*)query)[(j0 + jj) * 25 + c];
                bf16x2 p;
                p[0] = (bf16_t)(v.x * W[100 + 2 * c] * L2E);
                p[1] = (bf16_t)(v.y * W[100 + 2 * c + 1] * L2E);
                *(bf16x2*)&dst[jj * 72 + 2 * c] = p;
            } else {
                bf16x2 p;
                p[0] = (bf16_t)(stats[ST_QTERM + j0 + jj] * L2E);
                p[1] = (bf16_t)L2E;
                *(bf16x2*)&dst[jj * 72 + 50] = p;
            }
        }
    };
    auto stageQTT = [&](int jt, int buf, int tbase, int tn) {  // raw q^T
        const int j0 = jt * 64;
        bf16_t* dst = lb + QTT_E + buf * 4608;
        for (int e = tid - tbase; e < 1600; e += tn) {
            int c = e >> 6, jj = e & 63;
            float2 v = ((const float2*)query)[(j0 + jj) * 25 + c];
            dst[(2 * c) * 72 + jj]     = (bf16_t)v.x;
            dst[(2 * c + 1) * 72 + jj] = (bf16_t)v.y;
        }
    };

    // ---------------- setup phase 1 ----------------
    for (int e = tid; e < 924; e += 1024) {               // SENT pad rows 50..63
        int f = 50 + e / 66, c4 = (e - (e / 66) * 66) * 4;
        *(bf16x4*)&lb[SENT_E + f * 264 + c4] = (bf16x4){(bf16_t)0.f,(bf16_t)0.f,(bf16_t)0.f,(bf16_t)0.f};
    }
    for (int e = tid; e < 768; e += 1024) {               // sen K-pad cols 52..63
        int i = e / 3, c4 = 52 + (e - (e / 3) * 3) * 4;
        *(bf16x4*)&lb[PD0_E + i * 72 + c4] = (bf16x4){(bf16_t)0.f,(bf16_t)0.f,(bf16_t)0.f,(bf16_t)0.f};
    }
    for (int e = tid; e < 384; e += 1024) {               // QW3 pad cols (both bufs)
        int b = e / 192, r = e - b * 192;
        int jj = r / 3, c4 = 52 + (r - (r / 3) * 3) * 4;
        *(bf16x4*)&lb[QW3_E + b * 4608 + jj * 72 + c4] = (bf16x4){(bf16_t)0.f,(bf16_t)0.f,(bf16_t)0.f,(bf16_t)0.f};
    }
    for (int e = tid; e < 504; e += 1024) {               // QTT pad rows (both bufs)
        int b = e / 252, r = e - b * 252;
        int f = 50 + r / 18, c4 = (r - (r / 18) * 18) * 4;
        *(bf16x4*)&lb[QTT_E + b * 4608 + f * 72 + c4] = (bf16x4){(bf16_t)0.f,(bf16_t)0.f,(bf16_t)0.f,(bf16_t)0.f};
    }
    for (int e = tid; e < 256 * 25; e += 1024) {          // doc -> sen[i][f] + sen^T
        int i = e / 25, c = e - i * 25;
        float2 v = ((const float2*)sen_g)[i * 25 + c];
        bf16x2 p; p[0] = (bf16_t)v.x; p[1] = (bf16_t)v.y;
        *(bf16x2*)&lb[PD0_E + i * 72 + 2 * c] = p;
        lb[SENT_E + (2 * c) * 264 + i]     = p[0];
        lb[SENT_E + (2 * c + 1) * 264 + i] = p[1];
    }
    if (tid < NQ) {                                       // qterm = q . w2
        float acc = 0.f;
        #pragma unroll
        for (int c = 0; c < 25; ++c) {
            float2 v = ((const float2*)query)[tid * 25 + c];
            acc += v.x * W[NF + 2 * c] + v.y * W[NF + 2 * c + 1];
        }
        stats[ST_QTERM + tid] = acc;
    }
    if (tid < ND) {                                       // bias cols: 1, senw1
        float acc = 0.f;
        #pragma unroll
        for (int f = 0; f < NF; ++f) acc += sen_g[tid * NF + f] * W[f];
        lb[PD0_E + tid * 72 + 50] = (bf16_t)1.0f;
        lb[PD0_E + tid * 72 + 51] = (bf16_t)acc;
    }
    __syncthreads();

    // ---------------- setup phase 2 ----------------
    bf16x8 aS[2];
    #pragma unroll
    for (int ks = 0; ks < 2; ++ks)
        aS[ks] = *(bf16x8*)&lb[PD0_E + (w * 16 + ln) * 72 + lg * 8 + ks * 32];
    stageQW3(0, 0, 0, 1024);
    stageQTT(0, 0, 0, 1024);
    __syncthreads();

    // ---------------- single fused pass, 2 barriers/tile ----------------
    f32x4 accD[4];
    f32x4 K[16];
    #pragma unroll
    for (int nf = 0; nf < 4; ++nf) accD[nf] = (f32x4){0.f, 0.f, 0.f, 0.f};
    #pragma unroll
    for (int ib = 0; ib < 16; ++ib) K[ib] = (f32x4){0.f, 0.f, 0.f, 0.f};
    float rpart[4] = {0.f, 0.f, 0.f, 0.f};

    for (int jt = 0; jt < 8; ++jt) {
        // -------- consume tile jt-1: accD += (E ci)@q^T, K += (E ci)@E^T ----
        if (jt > 0) {
            const int pb = (jt - 1) & 1;
            const bf16_t* pdp = lb + (pb ? PD1_E : PD0_E);
            const bf16_t* qtp = lb + QTT_E + pb * 4608;
            bf16x8 aPs[2];
            #pragma unroll
            for (int ks = 0; ks < 2; ++ks) {
                bf16x8 raw = *(bf16x8*)&pdp[(w * 16 + ln) * 72 + lg * 8 + ks * 32];
                float4 c0 = *(const float4*)&stats[ST_CI + lg * 8 + ks * 32];
                float4 c1 = *(const float4*)&stats[ST_CI + lg * 8 + ks * 32 + 4];
                aPs[ks][0] = (bf16_t)((float)raw[0] * c0.x);
                aPs[ks][1] = (bf16_t)((float)raw[1] * c0.y);
                aPs[ks][2] = (bf16_t)((float)raw[2] * c0.z);
                aPs[ks][3] = (bf16_t)((float)raw[3] * c0.w);
                aPs[ks][4] = (bf16_t)((float)raw[4] * c1.x);
                aPs[ks][5] = (bf16_t)((float)raw[5] * c1.y);
                aPs[ks][6] = (bf16_t)((float)raw[6] * c1.z);
                aPs[ks][7] = (bf16_t)((float)raw[7] * c1.w);
            }
            #pragma unroll
            for (int ks = 0; ks < 2; ++ks)
                #pragma unroll
                for (int nf = 0; nf < 4; ++nf) {
                    bf16x8 bq = *(bf16x8*)&qtp[(nf * 16 + ln) * 72 + lg * 8 + ks * 32];
                    accD[nf] = MFMA16(aPs[ks], bq, accD[nf]);
                }
            #pragma unroll
            for (int ib = 0; ib < 16; ++ib)
                #pragma unroll
                for (int ks = 0; ks < 2; ++ks) {
                    bf16x8 bb = *(bf16x8*)&pdp[(ib * 16 + ln) * 72 + lg * 8 + ks * 32];
                    K[ib] = MFMA16(aPs[ks], bb, K[ib]);
                }
        }

        // -------- S(jt) -> raw E -> pd + col partials --------
        const bf16_t* qb = lb + QW3_E + (jt & 1) * 4608;
        bf16_t* pd = lb + ((jt & 1) ? PD1_E : PD0_E);
        f32x4 acc[4];
        #pragma unroll
        for (int nf = 0; nf < 4; ++nf) acc[nf] = (f32x4){-SHIFT, -SHIFT, -SHIFT, -SHIFT};
        #pragma unroll
        for (int ks = 0; ks < 2; ++ks)
            #pragma unroll
            for (int nf = 0; nf < 4; ++nf) {
                bf16x8 b = *(bf16x8*)&qb[(nf * 16 + ln) * 72 + lg * 8 + ks * 32];
                acc[nf] = MFMA16(aS[ks], b, acc[nf]);
            }
        #pragma unroll
        for (int nf = 0; nf < 4; ++nf) {
            #pragma unroll
            for (int r = 0; r < 4; ++r) acc[nf][r] = exp2f(acc[nf][r]);  // in place
            float cp = (acc[nf][0] + acc[nf][1]) + (acc[nf][2] + acc[nf][3]);
            cp += __shfl_xor(cp, 16);
            cp += __shfl_xor(cp, 32);
            if (lg == 0) part[w * 64 + nf * 16 + ln] = cp;
            #pragma unroll
            for (int r = 0; r < 4; ++r) {
                rpart[r] += acc[nf][r];
                pd[(w * 16 + lg * 4 + r) * 72 + nf * 16 + ln] = (bf16_t)acc[nf][r];
            }
        }
        __syncthreads();                                  // A: pd + partials visible

        if (w == 0) {
            float cs = 0.f;
            #pragma unroll
            for (int ww = 0; ww < 16; ++ww) cs += part[ww * 64 + l];
            stats[ST_CI + l] = 1.f / cs;
        } else if (jt < 7) {
            stageQW3(jt + 1, (jt + 1) & 1, 64, 960);
            stageQTT(jt + 1, (jt + 1) & 1, 64, 960);
        }
        __syncthreads();                                  // B: ci + staged bufs
    }

    // -------- final consume (tile 7) --------
    {
        const bf16_t* pdp = lb + PD1_E;
        const bf16_t* qtp = lb + QTT_E + 4608;
        bf16x8 aPs[2];
        #pragma unroll
        for (int ks = 0; ks < 2; ++ks) {
            bf16x8 raw = *(bf16x8*)&pdp[(w * 16 + ln) * 72 + lg * 8 + ks * 32];
            float4 c0 = *(const float4*)&stats[ST_CI + lg * 8 + ks * 32];
            float4 c1 = *(const float4*)&stats[ST_CI + lg * 8 + ks * 32 + 4];
            aPs[ks][0] = (bf16_t)((float)raw[0] * c0.x);
            aPs[ks][1] = (bf16_t)((float)raw[1] * c0.y);
            aPs[ks][2] = (bf16_t)((float)raw[2] * c0.z);
            aPs[ks][3] = (bf16_t)((float)raw[3] * c0.w);
            aPs[ks][4] = (bf16_t)((float)raw[4] * c1.x);
            aPs[ks][5] = (bf16_t)((float)raw[5] * c1.y);
            aPs[ks][6] = (bf16_t)((float)raw[6] * c1.z);
            aPs[ks][7] = (bf16_t)((float)raw[7] * c1.w);
        }
        #pragma unroll
        for (int ks = 0; ks < 2; ++ks)
            #pragma unroll
            for (int nf = 0; nf < 4; ++nf) {
                bf16x8 bq = *(bf16x8*)&qtp[(nf * 16 + ln) * 72 + lg * 8 + ks * 32];
                accD[nf] = MFMA16(aPs[ks], bq, accD[nf]);
            }
        #pragma unroll
        for (int ib = 0; ib < 16; ++ib)
            #pragma unroll
            for (int ks = 0; ks < 2; ++ks) {
                bf16x8 bb = *(bf16x8*)&pdp[(ib * 16 + ln) * 72 + lg * 8 + ks * 32];
                K[ib] = MFMA16(aPs[ks], bb, K[ib]);
            }
    }

    // ---------------- rinv ----------------
    #pragma unroll
    for (int r = 0; r < 4; ++r) {
        float v = rpart[r];
        v += __shfl_xor(v, 1);
        v += __shfl_xor(v, 2);
        v += __shfl_xor(v, 4);
        v += __shfl_xor(v, 8);
        if (ln == 0) stats[ST_RINV + w * 16 + lg * 4 + r] = 1.f / v;
    }
    __syncthreads();

    // ---------------- aQ2D = (ri*K) @ sen^T, 8 chunks ----------------
    f32x4 accQ[4];
    #pragma unroll
    for (int nf = 0; nf < 4; ++nf) accQ[nf] = (f32x4){0.f, 0.f, 0.f, 0.f};
    #pragma unroll
    for (int kt = 0; kt < 8; ++kt) {
        bf16_t* kl = lb + ((kt & 1) ? KL1_E : KL0_E);
        #pragma unroll
        for (int h = 0; h < 2; ++h) {
            const int ib = 2 * kt + h;
            float riv = stats[ST_RINV + ib * 16 + ln];
            #pragma unroll
            for (int r = 0; r < 4; ++r)
                kl[(w * 16 + lg * 4 + r) * 40 + h * 16 + ln] = (bf16_t)(K[ib][r] * riv);
        }
        __syncthreads();
        bf16x8 aK = *(bf16x8*)&kl[(w * 16 + ln) * 40 + lg * 8];
        #pragma unroll
        for (int nf = 0; nf < 4; ++nf) {
            bf16x8 b = *(bf16x8*)&lb[SENT_E + (nf * 16 + ln) * 264 + kt * 32 + lg * 8];
            accQ[nf] = MFMA16(aK, b, accQ[nf]);
        }
    }
    __syncthreads();

    // ---------------- epilogue ----------------
    float* ea = (float*)smem;                  // [256][68]
    float* eb = (float*)(smem + 69632);
    #pragma unroll
    for (int nf = 0; nf < 4; ++nf)
        #pragma unroll
        for (int r = 0; r < 4; ++r) {
            ea[(w * 16 + lg * 4 + r) * 68 + nf * 16 + ln] = accD[nf][r];
            eb[(w * 16 + lg * 4 + r) * 68 + nf * 16 + ln] = accQ[nf][r];
        }
    __syncthreads();
    const size_t ob0 = (size_t)s * (ND * 200);
    #pragma unroll
    for (int seg = 0; seg < 4; ++seg) {
        for (int v = tid; v < 6400; v += 1024) {
            int i = v / 25, c = v - (v / 25) * 25;
            int f = 2 * c;
            float2 o;
            if (seg == 0) {
                o = *(const float2*)&sen_g[i * 50 + f];
            } else if (seg == 1) {
                o.x = ea[i * 68 + f]; o.y = ea[i * 68 + f + 1];
            } else if (seg == 2) {
                float2 d = *(const float2*)&sen_g[i * 50 + f];
                o.x = d.x * ea[i * 68 + f]; o.y = d.y * ea[i * 68 + f + 1];
            } else {
                float2 d = *(const float2*)&sen_g[i * 50 + f];
                o.x = d.x * eb[i * 68 + f]; o.y = d.y * eb[i * 68 + f + 1];
            }
            *(float2*)&out[ob0 + (size_t)i * 200 + seg * 50 + f] = o;
        }
    }
}

extern "C" void kernel_launch(void* const* d_in, const int* in_sizes, int n_in,
                              void* d_out, int out_size, void* d_ws, size_t ws_size,
                              hipStream_t stream) {
    const float* query = (const float*)d_in[0];
    const float* doc   = (const float*)d_in[1];
    const float* W     = (const float*)d_in[2];
    float* out = (float*)d_out;
    (void)d_ws; (void)ws_size; (void)n_in; (void)in_sizes; (void)out_size;

    hipFuncSetAttribute((const void*)ca7_kernel,
                        hipFuncAttributeMaxDynamicSharedMemorySize,
                        LDS_BYTES);
    ca7_kernel<<<dim3(512), dim3(1024), LDS_BYTES, stream>>>(query, doc, W, out);
}

// Round 8
// 185.967 us; speedup vs baseline: 1.1242x; 1.0136x over previous
//
#include <hip/hip_runtime.h>
#include <math.h>

typedef __bf16 bf16_t;
typedef bf16_t bf16x2 __attribute__((ext_vector_type(2)));
typedef bf16_t bf16x4 __attribute__((ext_vector_type(4)));
typedef bf16_t bf16x8 __attribute__((ext_vector_type(8)));
typedef float f32x4 __attribute__((ext_vector_type(4)));

#define MFMA16(a,b,c) __builtin_amdgcn_mfma_f32_16x16x32_bf16((a),(b),(c),0,0,0)

#define ND 256
#define NQ 512
#define NF 50
#define L2E 1.44269504f
#define SHIFT 64.0f

// bf16-element offsets
#define SENT_E 0        // [64 f][264 i]  sen^T raw (rows 50..63 zero)
#define PD0_E  16896    // [256 i][72 j]  raw-E buf0 (setup alias: sen[i][72f]+bias)
#define PD1_E  35328    // [256 i][72 j]  raw-E buf1
#define QW3_E  53760    // 2 x [64 j][72 f] (q*w3*L2E + bias cols; 52..63 zero)
#define QTT_E  62976    // 2 x [64 f][72 j] raw q^T (rows 50..63 zero)
#define KL0_E  16896    // epilogue: [256 i][40] bf16 chunk buf0 (aliases PD0)
#define KL1_E  27136    // chunk buf1
#define PART_B  144384  // f32 [16 w][64 j] col partials
#define STATS_B 148480  // f32: qterm[512], ci[64], rinv[256]
#define LDS_BYTES 151808

#define ST_QTERM 0
#define ST_CI    512
#define ST_RINV  576

__attribute__((amdgpu_flat_work_group_size(1024, 1024)))
__attribute__((amdgpu_waves_per_eu(4, 4)))
__global__ void ca8_kernel(const float* __restrict__ query,
                           const float* __restrict__ doc,
                           const float* __restrict__ W,
                           float* __restrict__ out)
{
    extern __shared__ char smem[];
    bf16_t* lb = (bf16_t*)smem;
    float* part  = (float*)(smem + PART_B);
    float* stats = (float*)(smem + STATS_B);

    const int tid = threadIdx.x;
    const int w = tid >> 6, l = tid & 63, ln = l & 15, lg = l >> 4;
    const int s = blockIdx.x;
    const float* sen_g = doc + (size_t)s * (ND * NF);

    auto stageQW3 = [&](int jt, int buf, int tbase, int tn) {
        const int j0 = jt * 64;
        bf16_t* dst = lb + QW3_E + buf * 4608;
        for (int e = tid - tbase; e < 1664; e += tn) {
            int jj = e / 26, c = e - jj * 26;
            if (c < 25) {
                float2 v = ((const float2*)query)[(j0 + jj) * 25 + c];
                bf16x2 p;
                p[0] = (bf16_t)(v.x * W[100 + 2 * c] * L2E);
                p[1] = (bf16_t)(v.y * W[100 + 2 * c + 1] * L2E);
                *(bf16x2*)&dst[jj * 72 + 2 * c] = p;
            } else {
                bf16x2 p;
                p[0] = (bf16_t)(stats[ST_QTERM + j0 + jj] * L2E);
                p[1] = (bf16_t)L2E;
                *(bf16x2*)&dst[jj * 72 + 50] = p;
            }
        }
    };
    auto stageQTT = [&](int jt, int buf, int tbase, int tn) {  // raw q^T
        const int j0 = jt * 64;
        bf16_t* dst = lb + QTT_E + buf * 4608;
        for (int e = tid - tbase; e < 1600; e += tn) {
            int c = e >> 6, jj = e & 63;
            float2 v = ((const float2*)query)[(j0 + jj) * 25 + c];
            dst[(2 * c) * 72 + jj]     = (bf16_t)v.x;
            dst[(2 * c + 1) * 72 + jj] = (bf16_t)v.y;
        }
    };

    // ---------------- setup phase 1 ----------------
    for (int e = tid; e < 924; e += 1024) {               // SENT pad rows 50..63
        int f = 50 + e / 66, c4 = (e - (e / 66) * 66) * 4;
        *(bf16x4*)&lb[SENT_E + f * 264 + c4] = (bf16x4){(bf16_t)0.f,(bf16_t)0.f,(bf16_t)0.f,(bf16_t)0.f};
    }
    for (int e = tid; e < 768; e += 1024) {               // sen K-pad cols 52..63
        int i = e / 3, c4 = 52 + (e - (e / 3) * 3) * 4;
        *(bf16x4*)&lb[PD0_E + i * 72 + c4] = (bf16x4){(bf16_t)0.f,(bf16_t)0.f,(bf16_t)0.f,(bf16_t)0.f};
    }
    for (int e = tid; e < 384; e += 1024) {               // QW3 pad cols (both bufs)
        int b = e / 192, r = e - b * 192;
        int jj = r / 3, c4 = 52 + (r - (r / 3) * 3) * 4;
        *(bf16x4*)&lb[QW3_E + b * 4608 + jj * 72 + c4] = (bf16x4){(bf16_t)0.f,(bf16_t)0.f,(bf16_t)0.f,(bf16_t)0.f};
    }
    for (int e = tid; e < 504; e += 1024) {               // QTT pad rows (both bufs)
        int b = e / 252, r = e - b * 252;
        int f = 50 + r / 18, c4 = (r - (r / 18) * 18) * 4;
        *(bf16x4*)&lb[QTT_E + b * 4608 + f * 72 + c4] = (bf16x4){(bf16_t)0.f,(bf16_t)0.f,(bf16_t)0.f,(bf16_t)0.f};
    }
    for (int e = tid; e < 256 * 25; e += 1024) {          // doc -> sen[i][f] + sen^T
        int i = e / 25, c = e - i * 25;
        float2 v = ((const float2*)sen_g)[i * 25 + c];
        bf16x2 p; p[0] = (bf16_t)v.x; p[1] = (bf16_t)v.y;
        *(bf16x2*)&lb[PD0_E + i * 72 + 2 * c] = p;
        lb[SENT_E + (2 * c) * 264 + i]     = p[0];
        lb[SENT_E + (2 * c + 1) * 264 + i] = p[1];
    }
    if (tid < NQ) {                                       // qterm = q . w2
        float acc = 0.f;
        #pragma unroll
        for (int c = 0; c < 25; ++c) {
            float2 v = ((const float2*)query)[tid * 25 + c];
            acc += v.x * W[NF + 2 * c] + v.y * W[NF + 2 * c + 1];
        }
        stats[ST_QTERM + tid] = acc;
    }
    if (tid < ND) {                                       // bias cols: 1, senw1
        float acc = 0.f;
        #pragma unroll
        for (int f = 0; f < NF; ++f) acc += sen_g[tid * NF + f] * W[f];
        lb[PD0_E + tid * 72 + 50] = (bf16_t)1.0f;
        lb[PD0_E + tid * 72 + 51] = (bf16_t)acc;
    }
    __syncthreads();

    // ---------------- setup phase 2 ----------------
    bf16x8 aS[2];
    #pragma unroll
    for (int ks = 0; ks < 2; ++ks)
        aS[ks] = *(bf16x8*)&lb[PD0_E + (w * 16 + ln) * 72 + lg * 8 + ks * 32];
    stageQW3(0, 0, 0, 1024);
    stageQTT(0, 0, 0, 1024);
    __syncthreads();

    // ---------------- single fused pass, 2 barriers/tile ----------------
    f32x4 accD[4];
    f32x4 K[16];
    #pragma unroll
    for (int nf = 0; nf < 4; ++nf) accD[nf] = (f32x4){0.f, 0.f, 0.f, 0.f};
    #pragma unroll
    for (int ib = 0; ib < 16; ++ib) K[ib] = (f32x4){0.f, 0.f, 0.f, 0.f};
    float rpart[4] = {0.f, 0.f, 0.f, 0.f};

    for (int jt = 0; jt < 8; ++jt) {
        // -------- consume tile jt-1: accD += (E ci)@q^T, K += (E ci)@E^T ----
        if (jt > 0) {
            const int pb = (jt - 1) & 1;
            const bf16_t* pdp = lb + (pb ? PD1_E : PD0_E);
            const bf16_t* qtp = lb + QTT_E + pb * 4608;
            bf16x8 aPs[2];
            #pragma unroll
            for (int ks = 0; ks < 2; ++ks) {
                bf16x8 raw = *(bf16x8*)&pdp[(w * 16 + ln) * 72 + lg * 8 + ks * 32];
                float4 c0 = *(const float4*)&stats[ST_CI + lg * 8 + ks * 32];
                float4 c1 = *(const float4*)&stats[ST_CI + lg * 8 + ks * 32 + 4];
                aPs[ks][0] = (bf16_t)((float)raw[0] * c0.x);
                aPs[ks][1] = (bf16_t)((float)raw[1] * c0.y);
                aPs[ks][2] = (bf16_t)((float)raw[2] * c0.z);
                aPs[ks][3] = (bf16_t)((float)raw[3] * c0.w);
                aPs[ks][4] = (bf16_t)((float)raw[4] * c1.x);
                aPs[ks][5] = (bf16_t)((float)raw[5] * c1.y);
                aPs[ks][6] = (bf16_t)((float)raw[6] * c1.z);
                aPs[ks][7] = (bf16_t)((float)raw[7] * c1.w);
            }
            #pragma unroll
            for (int ks = 0; ks < 2; ++ks)
                #pragma unroll
                for (int nf = 0; nf < 4; ++nf) {
                    bf16x8 bq = *(bf16x8*)&qtp[(nf * 16 + ln) * 72 + lg * 8 + ks * 32];
                    accD[nf] = MFMA16(aPs[ks], bq, accD[nf]);
                }
            #pragma unroll
            for (int ib = 0; ib < 16; ++ib)
                #pragma unroll
                for (int ks = 0; ks < 2; ++ks) {
                    bf16x8 bb = *(bf16x8*)&pdp[(ib * 16 + ln) * 72 + lg * 8 + ks * 32];
                    K[ib] = MFMA16(aPs[ks], bb, K[ib]);
                }
        }

        // -------- S(jt) -> raw E -> pd + col partials --------
        const bf16_t* qb = lb + QW3_E + (jt & 1) * 4608;
        bf16_t* pd = lb + ((jt & 1) ? PD1_E : PD0_E);
        f32x4 acc[4];
        #pragma unroll
        for (int nf = 0; nf < 4; ++nf) acc[nf] = (f32x4){-SHIFT, -SHIFT, -SHIFT, -SHIFT};
        #pragma unroll
        for (int ks = 0; ks < 2; ++ks)
            #pragma unroll
            for (int nf = 0; nf < 4; ++nf) {
                bf16x8 b = *(bf16x8*)&qb[(nf * 16 + ln) * 72 + lg * 8 + ks * 32];
                acc[nf] = MFMA16(aS[ks], b, acc[nf]);
            }
        #pragma unroll
        for (int nf = 0; nf < 4; ++nf) {
            #pragma unroll
            for (int r = 0; r < 4; ++r) acc[nf][r] = exp2f(acc[nf][r]);  // in place
            float cp = (acc[nf][0] + acc[nf][1]) + (acc[nf][2] + acc[nf][3]);
            cp += __shfl_xor(cp, 16);
            cp += __shfl_xor(cp, 32);
            if (lg == 0) part[w * 64 + nf * 16 + ln] = cp;
            #pragma unroll
            for (int r = 0; r < 4; ++r) {
                rpart[r] += acc[nf][r];
                pd[(w * 16 + lg * 4 + r) * 72 + nf * 16 + ln] = (bf16_t)acc[nf][r];
            }
        }
        __syncthreads();                                  // A: pd + partials visible

        if (w == 0) {
            float cs = 0.f;
            #pragma unroll
            for (int ww = 0; ww < 16; ++ww) cs += part[ww * 64 + l];
            stats[ST_CI + l] = 1.f / cs;
        } else if (jt < 7) {
            stageQW3(jt + 1, (jt + 1) & 1, 64, 960);
            stageQTT(jt + 1, (jt + 1) & 1, 64, 960);
        }
        __syncthreads();                                  // B: ci + staged bufs
    }

    // -------- final consume (tile 7) --------
    {
        const bf16_t* pdp = lb + PD1_E;
        const bf16_t* qtp = lb + QTT_E + 4608;
        bf16x8 aPs[2];
        #pragma unroll
        for (int ks = 0; ks < 2; ++ks) {
            bf16x8 raw = *(bf16x8*)&pdp[(w * 16 + ln) * 72 + lg * 8 + ks * 32];
            float4 c0 = *(const float4*)&stats[ST_CI + lg * 8 + ks * 32];
            float4 c1 = *(const float4*)&stats[ST_CI + lg * 8 + ks * 32 + 4];
            aPs[ks][0] = (bf16_t)((float)raw[0] * c0.x);
            aPs[ks][1] = (bf16_t)((float)raw[1] * c0.y);
            aPs[ks][2] = (bf16_t)((float)raw[2] * c0.z);
            aPs[ks][3] = (bf16_t)((float)raw[3] * c0.w);
            aPs[ks][4] = (bf16_t)((float)raw[4] * c1.x);
            aPs[ks][5] = (bf16_t)((float)raw[5] * c1.y);
            aPs[ks][6] = (bf16_t)((float)raw[6] * c1.z);
            aPs[ks][7] = (bf16_t)((float)raw[7] * c1.w);
        }
        #pragma unroll
        for (int ks = 0; ks < 2; ++ks)
            #pragma unroll
            for (int nf = 0; nf < 4; ++nf) {
                bf16x8 bq = *(bf16x8*)&qtp[(nf * 16 + ln) * 72 + lg * 8 + ks * 32];
                accD[nf] = MFMA16(aPs[ks], bq, accD[nf]);
            }
        #pragma unroll
        for (int ib = 0; ib < 16; ++ib)
            #pragma unroll
            for (int ks = 0; ks < 2; ++ks) {
                bf16x8 bb = *(bf16x8*)&pdp[(ib * 16 + ln) * 72 + lg * 8 + ks * 32];
                K[ib] = MFMA16(aPs[ks], bb, K[ib]);
            }
    }

    // ---------------- rinv ----------------
    #pragma unroll
    for (int r = 0; r < 4; ++r) {
        float v = rpart[r];
        v += __shfl_xor(v, 1);
        v += __shfl_xor(v, 2);
        v += __shfl_xor(v, 4);
        v += __shfl_xor(v, 8);
        if (ln == 0) stats[ST_RINV + w * 16 + lg * 4 + r] = 1.f / v;
    }
    __syncthreads();

    // ---------------- aQ2D = (ri*K) @ sen^T, 8 chunks ----------------
    f32x4 accQ[4];
    #pragma unroll
    for (int nf = 0; nf < 4; ++nf) accQ[nf] = (f32x4){0.f, 0.f, 0.f, 0.f};
    #pragma unroll
    for (int kt = 0; kt < 8; ++kt) {
        bf16_t* kl = lb + ((kt & 1) ? KL1_E : KL0_E);
        #pragma unroll
        for (int h = 0; h < 2; ++h) {
            const int ib = 2 * kt + h;
            float riv = stats[ST_RINV + ib * 16 + ln];
            #pragma unroll
            for (int r = 0; r < 4; ++r)
                kl[(w * 16 + lg * 4 + r) * 40 + h * 16 + ln] = (bf16_t)(K[ib][r] * riv);
        }
        __syncthreads();
        bf16x8 aK = *(bf16x8*)&kl[(w * 16 + ln) * 40 + lg * 8];
        #pragma unroll
        for (int nf = 0; nf < 4; ++nf) {
            bf16x8 b = *(bf16x8*)&lb[SENT_E + (nf * 16 + ln) * 264 + kt * 32 + lg * 8];
            accQ[nf] = MFMA16(aK, b, accQ[nf]);
        }
    }
    __syncthreads();

    // ---------------- epilogue ----------------
    float* ea = (float*)smem;                  // [256][68]
    float* eb = (float*)(smem + 69632);
    #pragma unroll
    for (int nf = 0; nf < 4; ++nf)
        #pragma unroll
        for (int r = 0; r < 4; ++r) {
            ea[(w * 16 + lg * 4 + r) * 68 + nf * 16 + ln] = accD[nf][r];
            eb[(w * 16 + lg * 4 + r) * 68 + nf * 16 + ln] = accQ[nf][r];
        }
    __syncthreads();
    const size_t ob0 = (size_t)s * (ND * 200);
    #pragma unroll
    for (int seg = 0; seg < 4; ++seg) {
        for (int v = tid; v < 6400; v += 1024) {
            int i = v / 25, c = v - (v / 25) * 25;
            int f = 2 * c;
            float2 o;
            if (seg == 0) {
                o = *(const float2*)&sen_g[i * 50 + f];
            } else if (seg == 1) {
                o.x = ea[i * 68 + f]; o.y = ea[i * 68 + f + 1];
            } else if (seg == 2) {
                float2 d = *(const float2*)&sen_g[i * 50 + f];
                o.x = d.x * ea[i * 68 + f]; o.y = d.y * ea[i * 68 + f + 1];
            } else {
                float2 d = *(const float2*)&sen_g[i * 50 + f];
                o.x = d.x * eb[i * 68 + f]; o.y = d.y * eb[i * 68 + f + 1];
            }
            *(float2*)&out[ob0 + (size_t)i * 200 + seg * 50 + f] = o;
        }
    }
}

extern "C" void kernel_launch(void* const* d_in, const int* in_sizes, int n_in,
                              void* d_out, int out_size, void* d_ws, size_t ws_size,
                              hipStream_t stream) {
    const float* query = (const float*)d_in[0];
    const float* doc   = (const float*)d_in[1];
    const float* W     = (const float*)d_in[2];
    float* out = (float*)d_out;
    (void)d_ws; (void)ws_size; (void)n_in; (void)in_sizes; (void)out_size;

    hipFuncSetAttribute((const void*)ca8_kernel,
                        hipFuncAttributeMaxDynamicSharedMemorySize,
                        LDS_BYTES);
    ca8_kernel<<<dim3(512), dim3(1024), LDS_BYTES, stream>>>(query, doc, W, out);
}

// Round 9
// 132.614 us; speedup vs baseline: 1.5765x; 1.4023x over previous
//
#include <hip/hip_runtime.h>
#include <math.h>

typedef __bf16 bf16_t;
typedef bf16_t bf16x2 __attribute__((ext_vector_type(2)));
typedef bf16_t bf16x4 __attribute__((ext_vector_type(4)));
typedef bf16_t bf16x8 __attribute__((ext_vector_type(8)));
typedef float f32x4 __attribute__((ext_vector_type(4)));

#define MFMA16(a,b,c) __builtin_amdgcn_mfma_f32_16x16x32_bf16((a),(b),(c),0,0,0)

#define ND 256
#define NQ 512
#define NF 50
#define L2E 1.44269504f
#define SHIFT 64.0f

// bf16-element offsets
#define SENT_E 0        // [64 f][264 i]  sen^T raw (rows 50..63 zero)  bytes 0..33791
#define PD0_E  16896    // [256 i][72 j]  raw-E buf0                    bytes 33792..70655
#define PD1_E  35328    // [256 i][72 j]  raw-E buf1                    bytes 70656..107519
#define QW3_E  53760    // 2 x [64 j][72 f]                             bytes 107520..125951
#define QTT_E  62976    // 2 x [64 f][72 j] raw q^T                     bytes 125952..144383
#define KL0_E  16896    // epilogue chunk buf0 [256][40] bf16           bytes 33792..54271
#define KL1_E  27136    // chunk buf1                                   bytes 54272..74751
#define EA_B   74752    // epilogue accD f32 [256][68]                  bytes 74752..144383
#define PART_B  144384  // f32 [16 w][64 j] col partials
#define STATS_B 148480  // f32: qterm[512], ci[64], rinv[256]
#define LDS_BYTES 151808

#define ST_QTERM 0
#define ST_CI    512
#define ST_RINV  576

__launch_bounds__(1024, 4)
__global__ void ca9_kernel(const float* __restrict__ query,
                           const float* __restrict__ doc,
                           const float* __restrict__ W,
                           float* __restrict__ out)
{
    extern __shared__ char smem[];
    bf16_t* lb = (bf16_t*)smem;
    float* part  = (float*)(smem + PART_B);
    float* stats = (float*)(smem + STATS_B);

    const int tid = threadIdx.x;
    const int w = tid >> 6, l = tid & 63, ln = l & 15, lg = l >> 4;
    const int s = blockIdx.x;
    const float* sen_g = doc + (size_t)s * (ND * NF);

    auto stageQW3 = [&](int jt, int buf, int tbase, int tn) {
        const int j0 = jt * 64;
        bf16_t* dst = lb + QW3_E + buf * 4608;
        for (int e = tid - tbase; e < 1664; e += tn) {
            int jj = e / 26, c = e - jj * 26;
            if (c < 25) {
                float2 v = ((const float2*)query)[(j0 + jj) * 25 + c];
                bf16x2 p;
                p[0] = (bf16_t)(v.x * W[100 + 2 * c] * L2E);
                p[1] = (bf16_t)(v.y * W[100 + 2 * c + 1] * L2E);
                *(bf16x2*)&dst[jj * 72 + 2 * c] = p;
            } else {
                bf16x2 p;
                p[0] = (bf16_t)(stats[ST_QTERM + j0 + jj] * L2E);
                p[1] = (bf16_t)L2E;
                *(bf16x2*)&dst[jj * 72 + 50] = p;
            }
        }
    };
    auto stageQTT = [&](int jt, int buf, int tbase, int tn) {  // raw q^T
        const int j0 = jt * 64;
        bf16_t* dst = lb + QTT_E + buf * 4608;
        for (int e = tid - tbase; e < 1600; e += tn) {
            int c = e >> 6, jj = e & 63;
            float2 v = ((const float2*)query)[(j0 + jj) * 25 + c];
            dst[(2 * c) * 72 + jj]     = (bf16_t)v.x;
            dst[(2 * c + 1) * 72 + jj] = (bf16_t)v.y;
        }
    };

    // ---------------- setup phase 1 ----------------
    for (int e = tid; e < 924; e += 1024) {               // SENT pad rows 50..63
        int f = 50 + e / 66, c4 = (e - (e / 66) * 66) * 4;
        *(bf16x4*)&lb[SENT_E + f * 264 + c4] = (bf16x4){(bf16_t)0.f,(bf16_t)0.f,(bf16_t)0.f,(bf16_t)0.f};
    }
    for (int e = tid; e < 768; e += 1024) {               // sen K-pad cols 52..63
        int i = e / 3, c4 = 52 + (e - (e / 3) * 3) * 4;
        *(bf16x4*)&lb[PD0_E + i * 72 + c4] = (bf16x4){(bf16_t)0.f,(bf16_t)0.f,(bf16_t)0.f,(bf16_t)0.f};
    }
    for (int e = tid; e < 384; e += 1024) {               // QW3 pad cols (both bufs)
        int b = e / 192, r = e - b * 192;
        int jj = r / 3, c4 = 52 + (r - (r / 3) * 3) * 4;
        *(bf16x4*)&lb[QW3_E + b * 4608 + jj * 72 + c4] = (bf16x4){(bf16_t)0.f,(bf16_t)0.f,(bf16_t)0.f,(bf16_t)0.f};
    }
    for (int e = tid; e < 504; e += 1024) {               // QTT pad rows (both bufs)
        int b = e / 252, r = e - b * 252;
        int f = 50 + r / 18, c4 = (r - (r / 18) * 18) * 4;
        *(bf16x4*)&lb[QTT_E + b * 4608 + f * 72 + c4] = (bf16x4){(bf16_t)0.f,(bf16_t)0.f,(bf16_t)0.f,(bf16_t)0.f};
    }
    for (int e = tid; e < 256 * 25; e += 1024) {          // doc -> sen[i][f] + sen^T
        int i = e / 25, c = e - i * 25;
        float2 v = ((const float2*)sen_g)[i * 25 + c];
        bf16x2 p; p[0] = (bf16_t)v.x; p[1] = (bf16_t)v.y;
        *(bf16x2*)&lb[PD0_E + i * 72 + 2 * c] = p;
        lb[SENT_E + (2 * c) * 264 + i]     = p[0];
        lb[SENT_E + (2 * c + 1) * 264 + i] = p[1];
    }
    if (tid < NQ) {                                       // qterm = q . w2
        float acc = 0.f;
        #pragma unroll
        for (int c = 0; c < 25; ++c) {
            float2 v = ((const float2*)query)[tid * 25 + c];
            acc += v.x * W[NF + 2 * c] + v.y * W[NF + 2 * c + 1];
        }
        stats[ST_QTERM + tid] = acc;
    }
    if (tid < ND) {                                       // bias cols: 1, senw1
        float acc = 0.f;
        #pragma unroll
        for (int f = 0; f < NF; ++f) acc += sen_g[tid * NF + f] * W[f];
        lb[PD0_E + tid * 72 + 50] = (bf16_t)1.0f;
        lb[PD0_E + tid * 72 + 51] = (bf16_t)acc;
    }
    __syncthreads();

    // ---------------- setup phase 2 ----------------
    bf16x8 aS[2];
    #pragma unroll
    for (int ks = 0; ks < 2; ++ks)
        aS[ks] = *(bf16x8*)&lb[PD0_E + (w * 16 + ln) * 72 + lg * 8 + ks * 32];
    stageQW3(0, 0, 0, 1024);
    stageQTT(0, 0, 0, 1024);
    __syncthreads();

    // ---------------- single fused pass, symmetric K ----------------
    f32x4 accD[4];
    f32x4 K[9];                       // block cb=(w+d)&15, d=0..8 (d=8 iff w<8)
    #pragma unroll
    for (int nf = 0; nf < 4; ++nf) accD[nf] = (f32x4){0.f, 0.f, 0.f, 0.f};
    #pragma unroll
    for (int d = 0; d < 9; ++d) K[d] = (f32x4){0.f, 0.f, 0.f, 0.f};
    float rpart[4] = {0.f, 0.f, 0.f, 0.f};

    auto consumeTile = [&](const bf16_t* pdp, const bf16_t* qtp) {
        bf16x8 aPs[2];
        #pragma unroll
        for (int ks = 0; ks < 2; ++ks) {
            bf16x8 raw = *(bf16x8*)&pdp[(w * 16 + ln) * 72 + lg * 8 + ks * 32];
            float4 c0 = *(const float4*)&stats[ST_CI + lg * 8 + ks * 32];
            float4 c1 = *(const float4*)&stats[ST_CI + lg * 8 + ks * 32 + 4];
            aPs[ks][0] = (bf16_t)((float)raw[0] * c0.x);
            aPs[ks][1] = (bf16_t)((float)raw[1] * c0.y);
            aPs[ks][2] = (bf16_t)((float)raw[2] * c0.z);
            aPs[ks][3] = (bf16_t)((float)raw[3] * c0.w);
            aPs[ks][4] = (bf16_t)((float)raw[4] * c1.x);
            aPs[ks][5] = (bf16_t)((float)raw[5] * c1.y);
            aPs[ks][6] = (bf16_t)((float)raw[6] * c1.z);
            aPs[ks][7] = (bf16_t)((float)raw[7] * c1.w);
        }
        #pragma unroll
        for (int ks = 0; ks < 2; ++ks)
            #pragma unroll
            for (int nf = 0; nf < 4; ++nf) {
                bf16x8 bq = *(bf16x8*)&qtp[(nf * 16 + ln) * 72 + lg * 8 + ks * 32];
                accD[nf] = MFMA16(aPs[ks], bq, accD[nf]);
            }
        #pragma unroll
        for (int d = 0; d < 9; ++d) {
            if (d < 8 || w < 8) {
                const int cb = (w + d) & 15;
                #pragma unroll
                for (int ks = 0; ks < 2; ++ks) {
                    bf16x8 bb = *(bf16x8*)&pdp[(cb * 16 + ln) * 72 + lg * 8 + ks * 32];
                    K[d] = MFMA16(aPs[ks], bb, K[d]);
                }
            }
        }
    };

    for (int jt = 0; jt < 8; ++jt) {
        if (jt > 0) {
            const int pb = (jt - 1) & 1;
            consumeTile(lb + (pb ? PD1_E : PD0_E), lb + QTT_E + pb * 4608);
        }

        // -------- S(jt) -> raw E -> pd + col partials --------
        const bf16_t* qb = lb + QW3_E + (jt & 1) * 4608;
        bf16_t* pd = lb + ((jt & 1) ? PD1_E : PD0_E);
        f32x4 acc[4];
        #pragma unroll
        for (int nf = 0; nf < 4; ++nf) acc[nf] = (f32x4){-SHIFT, -SHIFT, -SHIFT, -SHIFT};
        #pragma unroll
        for (int ks = 0; ks < 2; ++ks)
            #pragma unroll
            for (int nf = 0; nf < 4; ++nf) {
                bf16x8 b = *(bf16x8*)&qb[(nf * 16 + ln) * 72 + lg * 8 + ks * 32];
                acc[nf] = MFMA16(aS[ks], b, acc[nf]);
            }
        #pragma unroll
        for (int nf = 0; nf < 4; ++nf) {
            #pragma unroll
            for (int r = 0; r < 4; ++r) acc[nf][r] = exp2f(acc[nf][r]);
            float cp = (acc[nf][0] + acc[nf][1]) + (acc[nf][2] + acc[nf][3]);
            cp += __shfl_xor(cp, 16);
            cp += __shfl_xor(cp, 32);
            if (lg == 0) part[w * 64 + nf * 16 + ln] = cp;
            #pragma unroll
            for (int r = 0; r < 4; ++r) {
                rpart[r] += acc[nf][r];
                pd[(w * 16 + lg * 4 + r) * 72 + nf * 16 + ln] = (bf16_t)acc[nf][r];
            }
        }
        __syncthreads();                                  // A: pd + partials visible

        if (w == 0) {
            float cs = 0.f;
            #pragma unroll
            for (int ww = 0; ww < 16; ++ww) cs += part[ww * 64 + l];
            stats[ST_CI + l] = 1.f / cs;
        } else if (jt < 7) {
            stageQW3(jt + 1, (jt + 1) & 1, 64, 960);
            stageQTT(jt + 1, (jt + 1) & 1, 64, 960);
        }
        __syncthreads();                                  // B: ci + staged bufs
    }
    consumeTile(lb + PD1_E, lb + QTT_E + 4608);           // final consume (tile 7)

    // ---------------- rinv ----------------
    #pragma unroll
    for (int r = 0; r < 4; ++r) {
        float v = rpart[r];
        v += __shfl_xor(v, 1);
        v += __shfl_xor(v, 2);
        v += __shfl_xor(v, 4);
        v += __shfl_xor(v, 8);
        if (ln == 0) stats[ST_RINV + w * 16 + lg * 4 + r] = 1.f / v;
    }
    __syncthreads();                                      // PD/QTT dead, rinv visible

    // accD -> ea early (frees accumulators before accQ phase)
    float* ea = (float*)(smem + EA_B);                    // [256][68]
    #pragma unroll
    for (int nf = 0; nf < 4; ++nf)
        #pragma unroll
        for (int r = 0; r < 4; ++r)
            ea[(w * 16 + lg * 4 + r) * 68 + nf * 16 + ln] = accD[nf][r];

    // ---------------- aQ2D = (ri*K) @ sen^T, 8 chunks, symmetric fill -----
    f32x4 accQ[4];
    #pragma unroll
    for (int nf = 0; nf < 4; ++nf) accQ[nf] = (f32x4){0.f, 0.f, 0.f, 0.f};
    #pragma unroll
    for (int kt = 0; kt < 8; ++kt) {
        bf16_t* kl = lb + ((kt & 1) ? KL1_E : KL0_E);
        // direct blocks (w, cb) with cb in this chunk
        #pragma unroll
        for (int d = 0; d < 9; ++d) {
            if (d < 8 || w < 8) {
                const int cb = (w + d) & 15;
                if ((cb >> 1) == kt) {
                    const int h = cb & 1;
                    const float riv = stats[ST_RINV + cb * 16 + ln];
                    #pragma unroll
                    for (int r = 0; r < 4; ++r)
                        kl[(w * 16 + lg * 4 + r) * 40 + h * 16 + ln] =
                            (bf16_t)(K[d][r] * riv);
                }
            }
        }
        // transposed blocks (cb, w): this wave's column lands in chunk w>>1
        if ((w >> 1) == kt) {
            const int h = w & 1;
            float4 rv = *(const float4*)&stats[ST_RINV + w * 16 + lg * 4];
            #pragma unroll
            for (int d = 1; d < 9; ++d) {
                if (d < 8 || w < 8) {
                    const int cb = (w + d) & 15;
                    bf16x4 pk;
                    pk[0] = (bf16_t)(K[d][0] * rv.x);
                    pk[1] = (bf16_t)(K[d][1] * rv.y);
                    pk[2] = (bf16_t)(K[d][2] * rv.z);
                    pk[3] = (bf16_t)(K[d][3] * rv.w);
                    *(bf16x4*)&kl[(cb * 16 + ln) * 40 + h * 16 + lg * 4] = pk;
                }
            }
        }
        __syncthreads();
        bf16x8 aK = *(bf16x8*)&kl[(w * 16 + ln) * 40 + lg * 8];
        #pragma unroll
        for (int nf = 0; nf < 4; ++nf) {
            bf16x8 b = *(bf16x8*)&lb[SENT_E + (nf * 16 + ln) * 264 + kt * 32 + lg * 8];
            accQ[nf] = MFMA16(aK, b, accQ[nf]);
        }
    }
    __syncthreads();                                      // SENT/KL dead

    // ---------------- epilogue ----------------
    float* eb = (float*)smem;                             // [256][68]
    #pragma unroll
    for (int nf = 0; nf < 4; ++nf)
        #pragma unroll
        for (int r = 0; r < 4; ++r)
            eb[(w * 16 + lg * 4 + r) * 68 + nf * 16 + ln] = accQ[nf][r];
    __syncthreads();
    const size_t ob0 = (size_t)s * (ND * 200);
    #pragma unroll
    for (int seg = 0; seg < 4; ++seg) {
        for (int v = tid; v < 6400; v += 1024) {
            int i = v / 25, c = v - (v / 25) * 25;
            int f = 2 * c;
            float2 o;
            if (seg == 0) {
                o = *(const float2*)&sen_g[i * 50 + f];
            } else if (seg == 1) {
                o.x = ea[i * 68 + f]; o.y = ea[i * 68 + f + 1];
            } else if (seg == 2) {
                float2 d = *(const float2*)&sen_g[i * 50 + f];
                o.x = d.x * ea[i * 68 + f]; o.y = d.y * ea[i * 68 + f + 1];
            } else {
                float2 d = *(const float2*)&sen_g[i * 50 + f];
                o.x = d.x * eb[i * 68 + f]; o.y = d.y * eb[i * 68 + f + 1];
            }
            *(float2*)&out[ob0 + (size_t)i * 200 + seg * 50 + f] = o;
        }
    }
}

extern "C" void kernel_launch(void* const* d_in, const int* in_sizes, int n_in,
                              void* d_out, int out_size, void* d_ws, size_t ws_size,
                              hipStream_t stream) {
    const float* query = (const float*)d_in[0];
    const float* doc   = (const float*)d_in[1];
    const float* W     = (const float*)d_in[2];
    float* out = (float*)d_out;
    (void)d_ws; (void)ws_size; (void)n_in; (void)in_sizes; (void)out_size;

    hipFuncSetAttribute((const void*)ca9_kernel,
                        hipFuncAttributeMaxDynamicSharedMemorySize,
                        LDS_BYTES);
    ca9_kernel<<<dim3(512), dim3(1024), LDS_BYTES, stream>>>(query, doc, W, out);
}